// Round 10
// baseline (340.448 us; speedup 1.0000x reference)
//
#include <hip/hip_runtime.h>
#include <math.h>

#define N_ATOMS    30000
#define N_PAIRS    300000
#define CAP        48              // bucket capacity per atom; multiple of 16
#define NF         64
#define ND         20
#define K_ENV      1280            // 20nu * 64f (packed, no padding)
#define K_TOT      1344            // K_ENV + 64 self features
#define NKSTEP     42              // K_TOT / 32
#define KSH        21              // NKSTEP / 2 (per-wave K half in phase 2)
#define HARD_CUT   6.5f
#define BA         16              // atoms per block in main kernel
#define ESTRIDE    1352            // env row stride in u16 (1344+8 pad -> bank spread)
#define NM1        ((unsigned)(N_ATOMS - 1))
#define REP        8               // in-kernel repetitions for R21 probes

// inverse-distance quantization: invd in [1/6.5, 1/0.85] -> u16
#define INVD_LO    0.15384615385f
#define INVD_RANGE 1.02262443439f
#define QS         (65535.0f / INVD_RANGE)
#define DQ         (INVD_RANGE / 65535.0f)
#define NEXP2      (-0.7213475204444817f)   // -0.5 * log2(e)

typedef short    s16x8  __attribute__((ext_vector_type(8)));
typedef __bf16   bf16x8 __attribute__((ext_vector_type(8)));
typedef unsigned u32x4  __attribute__((ext_vector_type(4)));
typedef float    f32x4  __attribute__((ext_vector_type(4)));
typedef float    f32x16 __attribute__((ext_vector_type(16)));

typedef __attribute__((address_space(1))) const void gconst_void;
typedef __attribute__((address_space(3))) void       lds_void;

__device__ __forceinline__ unsigned short f2bf(float x) {
    union { float f; unsigned u; } v; v.f = x;
    unsigned r = v.u + 0x7fffu + ((v.u >> 16) & 1u);   // RNE
    return (unsigned short)(r >> 16);
}
__device__ __forceinline__ unsigned pkbf(float a, float b) {
    return (unsigned)f2bf(a) | ((unsigned)f2bf(b) << 16);
}
// sensitivity for one packed pair-slot, lane's nu.
__device__ __forceinline__ float senseval(unsigned w0, unsigned lcb, int kidx, int cnt,
                                          float zA, float zB, bool nuok) {
    float uu = (float)(w0 & 0xffffu);
    float z  = __builtin_fmaf(uu, zA, zB);            // z = invd*isig - musig
    float ar = __builtin_fmaf(z * z, NEXP2, __uint_as_float(lcb));
    float e  = __builtin_amdgcn_exp2f(ar);
    return (nuok && kidx < cnt) ? e : 0.0f;
}

// ---------------------------------------------------------------------------
// K0: prep (R14 layout: 42 WtB blocks, cnts, msr, xb16).
__global__ void k_prep(const float* __restrict__ iw, const float* __restrict__ wself,
                       const float* __restrict__ mu, const float* __restrict__ sigma,
                       const float* __restrict__ x,
                       unsigned short* __restrict__ WtB, int* __restrict__ cnts,
                       float2* __restrict__ msr, unsigned* __restrict__ xb16) {
    if (blockIdx.x < 42) {
        int idx = blockIdx.x * 256 + threadIdx.x;       // (ks*4+q)*64 + lane
        if (idx >= NKSTEP * 4 * 64) return;
        int l  = idx & 63;
        int q  = (idx >> 6) & 3;
        int ks = idx >> 8;
        int n  = q * 16 + (l & 15);
        int kb = ks * 32 + (l >> 4) * 8;
        u32x4 u;
        #pragma unroll
        for (int jj = 0; jj < 4; jj++) {
            unsigned short lo, hi;
            #pragma unroll
            for (int e = 0; e < 2; e++) {
                int k = kb + 2 * jj + e;
                float val;
                if (k < K_ENV) {
                    int t  = k / 640;
                    int rm = k - t * 640;
                    int g  = rm >> 7;
                    int c  = (rm & 127) >> 2;
                    int r  = k & 3;
                    int nu = 4 * g + r;
                    int f  = 2 * c + t;                  // even/odd tile split
                    val = iw[(nu * NF + n) * NF + f];
                } else {
                    val = wself[n * NF + (k - K_ENV)];
                }
                if (e == 0) lo = f2bf(val); else hi = f2bf(val);
            }
            u[jj] = (unsigned)lo | ((unsigned)hi << 16);
        }
        *(u32x4*)&WtB[idx * 8] = u;
    } else if (blockIdx.x < 160) {
        int i = (blockIdx.x - 42) * 256 + threadIdx.x;
        if (i < N_ATOMS) cnts[i] = 0;
    } else if (blockIdx.x == 160) {
        int i = threadIdx.x;
        if (i < ND) { float2 m; m.x = mu[i]; m.y = 1.0f / sigma[i]; msr[i] = m; }
    } else {
        int o = (blockIdx.x - 161) * 256 + threadIdx.x;  // uint4 of xb16
        if (o < N_ATOMS * 32 / 4) {
            int wbase = o * 4;
            const float* src = &x[(size_t)wbase * 2];
            float2 f0 = *(const float2*)(src);
            float2 f1 = *(const float2*)(src + 2);
            float2 f2 = *(const float2*)(src + 4);
            float2 f3 = *(const float2*)(src + 6);
            u32x4 u;
            u[0] = pkbf(f0.x, f0.y);
            u[1] = pkbf(f1.x, f1.y);
            u[2] = pkbf(f2.x, f2.y);
            u[3] = pkbf(f3.x, f3.y);
            *(u32x4*)&xb16[wbase] = u;
        }
    }
}

// ---------------------------------------------------------------------------
// K1: scatter pairs into per-atom buckets (unchanged).
__global__ void k_scatter(const int* __restrict__ first, const int* __restrict__ second,
                          const float* __restrict__ dist, int* __restrict__ cnts,
                          uint2* __restrict__ pk) {
    int p = (blockIdx.x * 256 + threadIdx.x) * 2;
    if (p >= N_PAIRS) return;
    int2   f2 = *(const int2*)&first[p];
    int2   s2 = *(const int2*)&second[p];
    float2 d2 = *(const float2*)&dist[p];
    {
        float d    = d2.x;
        float invd = 1.0f / d;
        float tq   = fmaxf((invd - INVD_LO) * QS + 0.5f, 0.0f);
        unsigned u = min((unsigned)tq, 65535u);
        float co   = __cosf(0.2416609733530613f * d);    // 0.5*pi/6.5
        float lc   = fmaxf(__log2f(co * co), -10000.0f);
        int pos = atomicAdd(&cnts[f2.x], 1);
        if (pos < CAP) {
            uint2 v; v.x = ((unsigned)s2.x << 16) | u; v.y = __float_as_uint(lc);
            pk[(size_t)f2.x * CAP + pos] = v;
        }
    }
    {
        float d    = d2.y;
        float invd = 1.0f / d;
        float tq   = fmaxf((invd - INVD_LO) * QS + 0.5f, 0.0f);
        unsigned u = min((unsigned)tq, 65535u);
        float co   = __cosf(0.2416609733530613f * d);
        float lc   = fmaxf(__log2f(co * co), -10000.0f);
        int pos = atomicAdd(&cnts[f2.y], 1);
        if (pos < CAP) {
            uint2 v; v.x = ((unsigned)s2.y << 16) | u; v.y = __float_as_uint(lc);
            pk[(size_t)f2.y * CAP + pos] = v;
        }
    }
}

// ---------------------------------------------------------------------------
// K2: verified 118.8us config (R14): BA=16, (512,6), pkl staging, 8-wave
// phase-2 split, 4-deep prefetch. UNCHANGED this round.
__global__ void __launch_bounds__(512, 6)
k_main(const unsigned* __restrict__ xb16, const int* __restrict__ cnts,
       const uint2* __restrict__ pk, const float2* __restrict__ msr,
       const unsigned short* __restrict__ WtB, const float* __restrict__ bself,
       float* __restrict__ out) {
    __shared__ unsigned short env[BA * ESTRIDE];          // 43264 B
    __shared__ uint2 pkl[BA * CAP];                       // 6144 B
    const int t  = threadIdx.x;
    const int w  = t >> 6;
    const int l  = t & 63;
    const int h  = l >> 5;
    const int cl = l & 31;
    const int a0 = blockIdx.x * BA;

    if (w < 6) {
        const char* gsrc = (const char*)(pk + (size_t)a0 * CAP) + (w * 64 + l) * 16;
        char* ldst = (char*)pkl + w * 1024;
        __builtin_amdgcn_global_load_lds((gconst_void*)gsrc, (lds_void*)ldst, 16, 0, 0);
    }

    float2 ms   = msr[min(cl, ND - 1)];
    const float isig = ms.y;
    const float zA   = DQ * isig;
    const float zB   = INVD_LO * isig - ms.x * isig;
    const bool  nuok = (cl < ND);
    const unsigned* xw = xb16 + cl;

    const int cntA = min(cnts[a0 + 2 * w + 0], CAP);
    const int cntB = min(cnts[a0 + 2 * w + 1], CAP);

    __syncthreads();

    #pragma unroll 1
    for (int ci = 0; ci < 2; ci++) {
        const int i = 2 * w + ci;
        const int a = a0 + i;
        const int cnt = ci ? cntB : cntA;
        const int nst = max((cnt + 15) >> 4, 1);
        const uint2* gb = &pkl[i * CAP];
        f32x16 acc0 = {0.f}, acc1 = {0.f};
        #pragma unroll 1
        for (int ks = 0; ks < nst; ks++) {
            const int k0 = ks * 16 + h * 8;
            const uint2* bp = gb + k0;
            uint4 q0 = *(const uint4*)(bp + 0);
            uint4 q1 = *(const uint4*)(bp + 2);
            uint4 q2 = *(const uint4*)(bp + 4);
            uint4 q3 = *(const uint4*)(bp + 6);
            unsigned g0 = xw[min(q0.x >> 16, NM1) * 32];
            unsigned g1 = xw[min(q0.z >> 16, NM1) * 32];
            unsigned g2 = xw[min(q1.x >> 16, NM1) * 32];
            unsigned g3 = xw[min(q1.z >> 16, NM1) * 32];
            unsigned g4 = xw[min(q2.x >> 16, NM1) * 32];
            unsigned g5 = xw[min(q2.z >> 16, NM1) * 32];
            unsigned g6 = xw[min(q3.x >> 16, NM1) * 32];
            unsigned g7 = xw[min(q3.z >> 16, NM1) * 32];
            u32x4 A, B0, B1;
            A[0] = pkbf(senseval(q0.x, q0.y, k0 + 0, cnt, zA, zB, nuok),
                        senseval(q0.z, q0.w, k0 + 1, cnt, zA, zB, nuok));
            A[1] = pkbf(senseval(q1.x, q1.y, k0 + 2, cnt, zA, zB, nuok),
                        senseval(q1.z, q1.w, k0 + 3, cnt, zA, zB, nuok));
            A[2] = pkbf(senseval(q2.x, q2.y, k0 + 4, cnt, zA, zB, nuok),
                        senseval(q2.z, q2.w, k0 + 5, cnt, zA, zB, nuok));
            A[3] = pkbf(senseval(q3.x, q3.y, k0 + 6, cnt, zA, zB, nuok),
                        senseval(q3.z, q3.w, k0 + 7, cnt, zA, zB, nuok));
            B0[0] = __builtin_amdgcn_perm(g1, g0, 0x05040100u);
            B0[1] = __builtin_amdgcn_perm(g3, g2, 0x05040100u);
            B0[2] = __builtin_amdgcn_perm(g5, g4, 0x05040100u);
            B0[3] = __builtin_amdgcn_perm(g7, g6, 0x05040100u);
            B1[0] = __builtin_amdgcn_perm(g1, g0, 0x07060302u);
            B1[1] = __builtin_amdgcn_perm(g3, g2, 0x07060302u);
            B1[2] = __builtin_amdgcn_perm(g5, g4, 0x07060302u);
            B1[3] = __builtin_amdgcn_perm(g7, g6, 0x07060302u);
            acc0 = __builtin_amdgcn_mfma_f32_32x32x16_bf16(
                       __builtin_bit_cast(bf16x8, A),
                       __builtin_bit_cast(bf16x8, B0), acc0, 0, 0, 0);
            acc1 = __builtin_amdgcn_mfma_f32_32x32x16_bf16(
                       __builtin_bit_cast(bf16x8, A),
                       __builtin_bit_cast(bf16x8, B1), acc1, 0, 0, 0);
        }
        unsigned short* er = &env[i * ESTRIDE];
        #pragma unroll
        for (int q = 0; q < 3; q++) {
            int g = 2 * q + h;
            if (g < 5) {
                uint2 v0, v1;
                v0.x = pkbf(acc0[4 * q + 0], acc0[4 * q + 1]);
                v0.y = pkbf(acc0[4 * q + 2], acc0[4 * q + 3]);
                v1.x = pkbf(acc1[4 * q + 0], acc1[4 * q + 1]);
                v1.y = pkbf(acc1[4 * q + 2], acc1[4 * q + 3]);
                *(uint2*)&er[g * 128 + cl * 4]       = v0;
                *(uint2*)&er[640 + g * 128 + cl * 4] = v1;
            }
        }
        unsigned sw = xb16[(size_t)a * 32 + (l >> 1)];
        er[K_ENV + l] = (unsigned short)(sw >> ((l & 1) * 16));
    }

    const int wq     = w & 3;
    const int ksbase = (w >> 2) * KSH;
    const unsigned short* wb = &WtB[((ksbase * 4 + wq) * 64 + l) * 8];
    s16x8 b0 = *(const s16x8*)(wb);
    s16x8 b1 = *(const s16x8*)(wb + 2048);
    s16x8 b2 = *(const s16x8*)(wb + 4096);
    s16x8 b3 = *(const s16x8*)(wb + 6144);
    float bs = (w < 4) ? bself[wq * 16 + (l & 15)] : 0.f;
    __syncthreads();

    {
        const int m16  = l & 15;
        const int quad = l >> 4;
        f32x4 acc = {0.f, 0.f, 0.f, 0.f};
        for (int kk = 0; kk < KSH; kk++) {
            int ks = ksbase + kk;
            s16x8 afrag = *(const s16x8*)&env[m16 * ESTRIDE + ks * 32 + quad * 8];
            s16x8 bcur = b0;
            b0 = b1; b1 = b2; b2 = b3;
            int nx = (kk + 4 < KSH) ? kk + 4 : KSH - 1;
            b3 = *(const s16x8*)(wb + (size_t)nx * 2048);
            acc = __builtin_amdgcn_mfma_f32_16x16x32_bf16(
                      __builtin_bit_cast(bf16x8, afrag),
                      __builtin_bit_cast(bf16x8, bcur), acc, 0, 0, 0);
        }
        float* red = (float*)pkl;
        if (w >= 4) {
            *(f32x4*)&red[((w - 4) * 64 + l) * 4] = acc;
        }
        __syncthreads();
        if (w < 4) {
            f32x4 other = *(const f32x4*)&red[(w * 64 + l) * 4];
            #pragma unroll
            for (int r = 0; r < 4; r++) {
                int row = quad * 4 + r;
                out[(size_t)(a0 + row) * NF + wq * 16 + m16] = acc[r] + other[r] + bs;
            }
        }
    }
}

// ---------------------------------------------------------------------------
// R21 PROBE 1: phase-1 workload x REP in ONE dispatch (surfaces counters in
// the top-5 table). Memory clobber between reps defeats hoisting/CSE.
__global__ void __launch_bounds__(512, 6)
k_rep1(const unsigned* __restrict__ xb16, const int* __restrict__ cnts,
       const uint2* __restrict__ pk, const float2* __restrict__ msr,
       float* __restrict__ out) {
    __shared__ unsigned short env[BA * ESTRIDE];
    __shared__ uint2 pkl[BA * CAP];
    const int t  = threadIdx.x;
    const int w  = t >> 6;
    const int l  = t & 63;
    const int h  = l >> 5;
    const int cl = l & 31;
    const int a0 = blockIdx.x * BA;

    float2 ms   = msr[min(cl, ND - 1)];
    const float isig = ms.y;
    const float zA   = DQ * isig;
    const float zB   = INVD_LO * isig - ms.x * isig;
    const bool  nuok = (cl < ND);
    const unsigned* xw = xb16 + cl;

    #pragma unroll 1
    for (int rep = 0; rep < REP; rep++) {
        if (w < 6) {
            const char* gsrc = (const char*)(pk + (size_t)a0 * CAP) + (w * 64 + l) * 16;
            char* ldst = (char*)pkl + w * 1024;
            __builtin_amdgcn_global_load_lds((gconst_void*)gsrc, (lds_void*)ldst, 16, 0, 0);
        }
        const int cntA = min(cnts[a0 + 2 * w + 0], CAP);
        const int cntB = min(cnts[a0 + 2 * w + 1], CAP);
        __syncthreads();                                  // pkl ready
        #pragma unroll 1
        for (int ci = 0; ci < 2; ci++) {
            const int i = 2 * w + ci;
            const int a = a0 + i;
            const int cnt = ci ? cntB : cntA;
            const int nst = max((cnt + 15) >> 4, 1);
            const uint2* gb = &pkl[i * CAP];
            f32x16 acc0 = {0.f}, acc1 = {0.f};
            #pragma unroll 1
            for (int ks = 0; ks < nst; ks++) {
                const int k0 = ks * 16 + h * 8;
                const uint2* bp = gb + k0;
                uint4 q0 = *(const uint4*)(bp + 0);
                uint4 q1 = *(const uint4*)(bp + 2);
                uint4 q2 = *(const uint4*)(bp + 4);
                uint4 q3 = *(const uint4*)(bp + 6);
                unsigned g0 = xw[min(q0.x >> 16, NM1) * 32];
                unsigned g1 = xw[min(q0.z >> 16, NM1) * 32];
                unsigned g2 = xw[min(q1.x >> 16, NM1) * 32];
                unsigned g3 = xw[min(q1.z >> 16, NM1) * 32];
                unsigned g4 = xw[min(q2.x >> 16, NM1) * 32];
                unsigned g5 = xw[min(q2.z >> 16, NM1) * 32];
                unsigned g6 = xw[min(q3.x >> 16, NM1) * 32];
                unsigned g7 = xw[min(q3.z >> 16, NM1) * 32];
                u32x4 A, B0, B1;
                A[0] = pkbf(senseval(q0.x, q0.y, k0 + 0, cnt, zA, zB, nuok),
                            senseval(q0.z, q0.w, k0 + 1, cnt, zA, zB, nuok));
                A[1] = pkbf(senseval(q1.x, q1.y, k0 + 2, cnt, zA, zB, nuok),
                            senseval(q1.z, q1.w, k0 + 3, cnt, zA, zB, nuok));
                A[2] = pkbf(senseval(q2.x, q2.y, k0 + 4, cnt, zA, zB, nuok),
                            senseval(q2.z, q2.w, k0 + 5, cnt, zA, zB, nuok));
                A[3] = pkbf(senseval(q3.x, q3.y, k0 + 6, cnt, zA, zB, nuok),
                            senseval(q3.z, q3.w, k0 + 7, cnt, zA, zB, nuok));
                B0[0] = __builtin_amdgcn_perm(g1, g0, 0x05040100u);
                B0[1] = __builtin_amdgcn_perm(g3, g2, 0x05040100u);
                B0[2] = __builtin_amdgcn_perm(g5, g4, 0x05040100u);
                B0[3] = __builtin_amdgcn_perm(g7, g6, 0x05040100u);
                B1[0] = __builtin_amdgcn_perm(g1, g0, 0x07060302u);
                B1[1] = __builtin_amdgcn_perm(g3, g2, 0x07060302u);
                B1[2] = __builtin_amdgcn_perm(g5, g4, 0x07060302u);
                B1[3] = __builtin_amdgcn_perm(g7, g6, 0x07060302u);
                acc0 = __builtin_amdgcn_mfma_f32_32x32x16_bf16(
                           __builtin_bit_cast(bf16x8, A),
                           __builtin_bit_cast(bf16x8, B0), acc0, 0, 0, 0);
                acc1 = __builtin_amdgcn_mfma_f32_32x32x16_bf16(
                           __builtin_bit_cast(bf16x8, A),
                           __builtin_bit_cast(bf16x8, B1), acc1, 0, 0, 0);
            }
            unsigned short* er = &env[i * ESTRIDE];
            #pragma unroll
            for (int q = 0; q < 3; q++) {
                int g = 2 * q + h;
                if (g < 5) {
                    uint2 v0, v1;
                    v0.x = pkbf(acc0[4 * q + 0], acc0[4 * q + 1]);
                    v0.y = pkbf(acc0[4 * q + 2], acc0[4 * q + 3]);
                    v1.x = pkbf(acc1[4 * q + 0], acc1[4 * q + 1]);
                    v1.y = pkbf(acc1[4 * q + 2], acc1[4 * q + 3]);
                    *(uint2*)&er[g * 128 + cl * 4]       = v0;
                    *(uint2*)&er[640 + g * 128 + cl * 4] = v1;
                }
            }
            unsigned sw = xb16[(size_t)a * 32 + (l >> 1)];
            er[K_ENV + l] = (unsigned short)(sw >> ((l & 1) * 16));
        }
        __syncthreads();                                  // all reads done
        asm volatile("" ::: "memory");                    // defeat cross-rep CSE
    }
    // env-dependent store keeps everything live (overwritten by real k_main)
    out[(size_t)(a0 + w) * NF + l] = (float)(short)env[t * 2 + (t & 1)];
}

// ---------------------------------------------------------------------------
// R21 PROBE 2: phase-2 workload x REP in ONE dispatch. env uninitialized
// (garbage values, perf-identical); acc chained across reps keeps MFMAs live.
__global__ void __launch_bounds__(512, 6)
k_rep2(const unsigned short* __restrict__ WtB, const float* __restrict__ bself,
       float* __restrict__ out) {
    __shared__ unsigned short env[BA * ESTRIDE];
    __shared__ uint2 pkl[BA * CAP];
    const int t  = threadIdx.x;
    const int w  = t >> 6;
    const int l  = t & 63;
    const int a0 = blockIdx.x * BA;
    const int wq     = w & 3;
    const int ksbase = (w >> 2) * KSH;
    const unsigned short* wb = &WtB[((ksbase * 4 + wq) * 64 + l) * 8];
    const int m16  = l & 15;
    const int quad = l >> 4;
    float bs = (w < 4) ? bself[wq * 16 + (l & 15)] : 0.f;
    // make env "written" so reads are well-defined
    for (int i = t; i < BA * ESTRIDE / 2; i += 512) ((unsigned*)env)[i] = i;
    __syncthreads();

    f32x4 acc = {0.f, 0.f, 0.f, 0.f};
    #pragma unroll 1
    for (int rep = 0; rep < REP; rep++) {
        s16x8 b0 = *(const s16x8*)(wb);
        s16x8 b1 = *(const s16x8*)(wb + 2048);
        s16x8 b2 = *(const s16x8*)(wb + 4096);
        s16x8 b3 = *(const s16x8*)(wb + 6144);
        for (int kk = 0; kk < KSH; kk++) {
            int ks = ksbase + kk;
            s16x8 afrag = *(const s16x8*)&env[m16 * ESTRIDE + ks * 32 + quad * 8];
            s16x8 bcur = b0;
            b0 = b1; b1 = b2; b2 = b3;
            int nx = (kk + 4 < KSH) ? kk + 4 : KSH - 1;
            b3 = *(const s16x8*)(wb + (size_t)nx * 2048);
            acc = __builtin_amdgcn_mfma_f32_16x16x32_bf16(
                      __builtin_bit_cast(bf16x8, afrag),
                      __builtin_bit_cast(bf16x8, bcur), acc, 0, 0, 0);
        }
        asm volatile("" ::: "memory");                    // defeat hoisting
    }
    // reduction + store, same shape as real phase-2 (garbage; overwritten)
    float* red = (float*)pkl;
    if (w >= 4) *(f32x4*)&red[((w - 4) * 64 + l) * 4] = acc;
    __syncthreads();
    if (w < 4) {
        f32x4 other = *(const f32x4*)&red[(w * 64 + l) * 4];
        #pragma unroll
        for (int r = 0; r < 4; r++) {
            int row = quad * 4 + r;
            out[(size_t)(a0 + row) * NF + wq * 16 + m16] = acc[r] + other[r] + bs;
        }
    }
}

// ---------------------------------------------------------------------------
extern "C" void kernel_launch(void* const* d_in, const int* in_sizes, int n_in,
                              void* d_out, int out_size, void* d_ws, size_t ws_size,
                              hipStream_t stream) {
    const float* x      = (const float*)d_in[0];
    const int*   first  = (const int*)d_in[1];
    const int*   second = (const int*)d_in[2];
    const float* dist   = (const float*)d_in[3];
    const float* mu     = (const float*)d_in[4];
    const float* sigma  = (const float*)d_in[5];
    const float* iw     = (const float*)d_in[6];
    const float* wself  = (const float*)d_in[7];
    const float* bself  = (const float*)d_in[8];
    float* out = (float*)d_out;

    char* ws = (char*)d_ws;
    unsigned short* WtB  = (unsigned short*)(ws);          // 172032 B
    int*            cnts = (int*)(ws + 172032);            // 120000 B
    float2*         msr  = (float2*)(ws + 292032);         // 160 B
    uint2*          pk   = (uint2*)(ws + 292192);          // 11520000 B
    unsigned*       xb16 = (unsigned*)(ws + 11812192);     // 3840000 B -> ~15.7 MB

    k_prep<<<dim3(161 + (N_ATOMS * 8 + 255) / 256), dim3(256), 0, stream>>>(
        iw, wself, mu, sigma, x, WtB, cnts, msr, xb16);
    k_scatter<<<dim3((N_PAIRS / 2 + 255) / 256), dim3(256), 0, stream>>>(
        first, second, dist, cnts, pk);
    // ---- R21 COUNTER PROBES (one long dispatch each -> top-5 visibility) ----
    k_rep1<<<dim3(N_ATOMS / BA), dim3(512), 0, stream>>>(xb16, cnts, pk, msr, out);
    k_rep2<<<dim3(N_ATOMS / BA), dim3(512), 0, stream>>>(WtB, bself, out);
    // real kernel LAST (overwrites probe output deterministically)
    k_main<<<dim3(N_ATOMS / BA), dim3(512), 0, stream>>>(
        xb16, cnts, pk, msr, WtB, bself, out);
}

// Round 11
// 117.165 us; speedup vs baseline: 2.9057x; 2.9057x over previous
//
#include <hip/hip_runtime.h>
#include <math.h>

#define N_ATOMS    30000
#define N_PAIRS    300000
#define CAP        48              // bucket capacity per atom; multiple of 16
#define NF         64
#define ND         20
#define K_ENV      1280            // 20nu * 64f (packed, no padding)
#define K_TOT      1344            // K_ENV + 64 self features
#define NKSTEP     42              // K_TOT / 32
#define KSH        21              // NKSTEP / 2 (per-wave K half in phase 2)
#define HARD_CUT   6.5f
#define BA         16              // atoms per block in main kernel
#define ESTRIDE    1352            // env row stride in u16 (1344+8 pad -> bank spread)
#define NM1        ((unsigned)(N_ATOMS - 1))

// inverse-distance quantization: invd in [1/6.5, 1/0.85] -> u16
#define INVD_LO    0.15384615385f
#define INVD_RANGE 1.02262443439f
#define QS         (65535.0f / INVD_RANGE)
#define DQ         (INVD_RANGE / 65535.0f)
#define NEXP2      (-0.7213475204444817f)   // -0.5 * log2(e)

typedef short    s16x8  __attribute__((ext_vector_type(8)));
typedef __bf16   bf16x8 __attribute__((ext_vector_type(8)));
typedef unsigned u32x4  __attribute__((ext_vector_type(4)));
typedef float    f32x4  __attribute__((ext_vector_type(4)));
typedef float    f32x16 __attribute__((ext_vector_type(16)));

typedef __attribute__((address_space(1))) const void gconst_void;
typedef __attribute__((address_space(3))) void       lds_void;

__device__ __forceinline__ unsigned short f2bf(float x) {
    union { float f; unsigned u; } v; v.f = x;
    unsigned r = v.u + 0x7fffu + ((v.u >> 16) & 1u);   // RNE
    return (unsigned short)(r >> 16);
}
// RNE pack (used in one-time prep only)
__device__ __forceinline__ unsigned pkbf(float a, float b) {
    return (unsigned)f2bf(a) | ((unsigned)f2bf(b) << 16);
}
// R22 FAST pack: round-half-up + v_perm -> 3 VALU (vs ~8 for RNE).
// Differs from RNE only on exact-tie mantissas (<=1 ULP). a in low 16.
__device__ __forceinline__ unsigned pkbf2(float a, float b) {
    unsigned au = __float_as_uint(a) + 0x8000u;
    unsigned bu = __float_as_uint(b) + 0x8000u;
    return __builtin_amdgcn_perm(bu, au, 0x07060302u);  // {bu.hi16, au.hi16}
}
// R22 sense: NO selects. Pad slots carry lcb=-inf (exp2 -> exact 0);
// nu>=20 lanes carry zA=0,zB=1e19 (z^2=1e38 finite -> ar<=-7e37 -> 0).
__device__ __forceinline__ float senseval(unsigned w0, unsigned lcb,
                                          float zA, float zB) {
    float uu = (float)(w0 & 0xffffu);
    float z  = __builtin_fmaf(uu, zA, zB);
    float ar = __builtin_fmaf(z * z, NEXP2, __uint_as_float(lcb));
    return __builtin_amdgcn_exp2f(ar);
}

// ---------------------------------------------------------------------------
// K0: prep (R14 layout: 42 WtB blocks, cnts, msr, xb16).
__global__ void k_prep(const float* __restrict__ iw, const float* __restrict__ wself,
                       const float* __restrict__ mu, const float* __restrict__ sigma,
                       const float* __restrict__ x,
                       unsigned short* __restrict__ WtB, int* __restrict__ cnts,
                       float2* __restrict__ msr, unsigned* __restrict__ xb16) {
    if (blockIdx.x < 42) {
        int idx = blockIdx.x * 256 + threadIdx.x;       // (ks*4+q)*64 + lane
        if (idx >= NKSTEP * 4 * 64) return;
        int l  = idx & 63;
        int q  = (idx >> 6) & 3;
        int ks = idx >> 8;
        int n  = q * 16 + (l & 15);
        int kb = ks * 32 + (l >> 4) * 8;
        u32x4 u;
        #pragma unroll
        for (int jj = 0; jj < 4; jj++) {
            unsigned short lo, hi;
            #pragma unroll
            for (int e = 0; e < 2; e++) {
                int k = kb + 2 * jj + e;
                float val;
                if (k < K_ENV) {
                    int t  = k / 640;
                    int rm = k - t * 640;
                    int g  = rm >> 7;
                    int c  = (rm & 127) >> 2;
                    int r  = k & 3;
                    int nu = 4 * g + r;
                    int f  = 2 * c + t;                  // even/odd tile split
                    val = iw[(nu * NF + n) * NF + f];
                } else {
                    val = wself[n * NF + (k - K_ENV)];
                }
                if (e == 0) lo = f2bf(val); else hi = f2bf(val);
            }
            u[jj] = (unsigned)lo | ((unsigned)hi << 16);
        }
        *(u32x4*)&WtB[idx * 8] = u;
    } else if (blockIdx.x < 160) {
        int i = (blockIdx.x - 42) * 256 + threadIdx.x;
        if (i < N_ATOMS) cnts[i] = 0;
    } else if (blockIdx.x == 160) {
        int i = threadIdx.x;
        if (i < ND) { float2 m; m.x = mu[i]; m.y = 1.0f / sigma[i]; msr[i] = m; }
    } else {
        int o = (blockIdx.x - 161) * 256 + threadIdx.x;  // uint4 of xb16
        if (o < N_ATOMS * 32 / 4) {
            int wbase = o * 4;
            const float* src = &x[(size_t)wbase * 2];
            float2 f0 = *(const float2*)(src);
            float2 f1 = *(const float2*)(src + 2);
            float2 f2 = *(const float2*)(src + 4);
            float2 f3 = *(const float2*)(src + 6);
            u32x4 u;
            u[0] = pkbf(f0.x, f0.y);
            u[1] = pkbf(f1.x, f1.y);
            u[2] = pkbf(f2.x, f2.y);
            u[3] = pkbf(f3.x, f3.y);
            *(u32x4*)&xb16[wbase] = u;
        }
    }
}

// ---------------------------------------------------------------------------
// K1: scatter pairs into per-atom buckets (unchanged).
__global__ void k_scatter(const int* __restrict__ first, const int* __restrict__ second,
                          const float* __restrict__ dist, int* __restrict__ cnts,
                          uint2* __restrict__ pk) {
    int p = (blockIdx.x * 256 + threadIdx.x) * 2;
    if (p >= N_PAIRS) return;
    int2   f2 = *(const int2*)&first[p];
    int2   s2 = *(const int2*)&second[p];
    float2 d2 = *(const float2*)&dist[p];
    {
        float d    = d2.x;
        float invd = 1.0f / d;
        float tq   = fmaxf((invd - INVD_LO) * QS + 0.5f, 0.0f);
        unsigned u = min((unsigned)tq, 65535u);
        float co   = __cosf(0.2416609733530613f * d);    // 0.5*pi/6.5
        float lc   = fmaxf(__log2f(co * co), -10000.0f);
        int pos = atomicAdd(&cnts[f2.x], 1);
        if (pos < CAP) {
            uint2 v; v.x = ((unsigned)s2.x << 16) | u; v.y = __float_as_uint(lc);
            pk[(size_t)f2.x * CAP + pos] = v;
        }
    }
    {
        float d    = d2.y;
        float invd = 1.0f / d;
        float tq   = fmaxf((invd - INVD_LO) * QS + 0.5f, 0.0f);
        unsigned u = min((unsigned)tq, 65535u);
        float co   = __cosf(0.2416609733530613f * d);
        float lc   = fmaxf(__log2f(co * co), -10000.0f);
        int pos = atomicAdd(&cnts[f2.y], 1);
        if (pos < CAP) {
            uint2 v; v.x = ((unsigned)s2.y << 16) | u; v.y = __float_as_uint(lc);
            pk[(size_t)f2.y * CAP + pos] = v;
        }
    }
}

// ---------------------------------------------------------------------------
// K2: 118.8us structure (R14) + R22 VALU diet, justified by R21 counters
// (phase-1 VALUBusy 77%, MfmaUtil 5%, FETCH ~5MB/rep -> pure VALU-issue-bound):
//  (a) pkbf2 pack (3 VALU) for A-matrix + env epilogue,
//  (b) pad slots [cnt,48) overwritten in LDS with {0, -inf} -> senseval has
//      ZERO selects and gathers need NO min-clamp,
//  (c) nu>=20 handled by constant poisoning (zA=0, zB=1e19).
__global__ void __launch_bounds__(512, 6)
k_main(const unsigned* __restrict__ xb16, const int* __restrict__ cnts,
       const uint2* __restrict__ pk, const float2* __restrict__ msr,
       const unsigned short* __restrict__ WtB, const float* __restrict__ bself,
       float* __restrict__ out) {
    __shared__ unsigned short env[BA * ESTRIDE];          // 43264 B
    __shared__ uint2 pkl[BA * CAP];                       // 6144 B
    const int t  = threadIdx.x;
    const int w  = t >> 6;
    const int l  = t & 63;
    const int h  = l >> 5;
    const int cl = l & 31;
    const int a0 = blockIdx.x * BA;

    if (w < 6) {
        const char* gsrc = (const char*)(pk + (size_t)a0 * CAP) + (w * 64 + l) * 16;
        char* ldst = (char*)pkl + w * 1024;
        __builtin_amdgcn_global_load_lds((gconst_void*)gsrc, (lds_void*)ldst, 16, 0, 0);
    }

    float2 ms   = msr[min(cl, ND - 1)];
    const bool  nuok = (cl < ND);
    const float isig = ms.y;
    const float zA   = nuok ? DQ * isig : 0.0f;           // poison: z const
    const float zB   = nuok ? (INVD_LO * isig - ms.x * isig) : 1.0e19f;
    const unsigned* xw = xb16 + cl;

    const int cntA = min(cnts[a0 + 2 * w + 0], CAP);
    const int cntB = min(cnts[a0 + 2 * w + 1], CAP);

    __syncthreads();                                      // pkl staged

    // pad-poison slots [cnt,CAP) of THIS wave's two atoms: second=0 (safe
    // gather row 0), lc=-inf (exp2 -> exact 0). Same-wave write->read: no
    // extra barrier needed.
    {
        uint2 pz; pz.x = 0u; pz.y = 0xFF800000u;
        if (l < CAP) {
            if (l >= cntA) pkl[(2 * w + 0) * CAP + l] = pz;
            if (l >= cntB) pkl[(2 * w + 1) * CAP + l] = pz;
        }
    }

    // ---- Phase 1: MFMA envsum (2 atoms per wave, sequential) ----
    #pragma unroll 1
    for (int ci = 0; ci < 2; ci++) {
        const int i = 2 * w + ci;
        const int a = a0 + i;
        const int cnt = ci ? cntB : cntA;
        const int nst = max((cnt + 15) >> 4, 1);
        const uint2* gb = &pkl[i * CAP];
        f32x16 acc0 = {0.f}, acc1 = {0.f};
        #pragma unroll 1
        for (int ks = 0; ks < nst; ks++) {
            const int k0 = ks * 16 + h * 8;
            const uint2* bp = gb + k0;
            uint4 q0 = *(const uint4*)(bp + 0);
            uint4 q1 = *(const uint4*)(bp + 2);
            uint4 q2 = *(const uint4*)(bp + 4);
            uint4 q3 = *(const uint4*)(bp + 6);
            // 8 dword gathers, NO clamp (pad second = 0)
            unsigned g0 = xw[(q0.x >> 16) * 32];
            unsigned g1 = xw[(q0.z >> 16) * 32];
            unsigned g2 = xw[(q1.x >> 16) * 32];
            unsigned g3 = xw[(q1.z >> 16) * 32];
            unsigned g4 = xw[(q2.x >> 16) * 32];
            unsigned g5 = xw[(q2.z >> 16) * 32];
            unsigned g6 = xw[(q3.x >> 16) * 32];
            unsigned g7 = xw[(q3.z >> 16) * 32];
            u32x4 A, B0, B1;
            A[0] = pkbf2(senseval(q0.x, q0.y, zA, zB),
                         senseval(q0.z, q0.w, zA, zB));
            A[1] = pkbf2(senseval(q1.x, q1.y, zA, zB),
                         senseval(q1.z, q1.w, zA, zB));
            A[2] = pkbf2(senseval(q2.x, q2.y, zA, zB),
                         senseval(q2.z, q2.w, zA, zB));
            A[3] = pkbf2(senseval(q3.x, q3.y, zA, zB),
                         senseval(q3.z, q3.w, zA, zB));
            B0[0] = __builtin_amdgcn_perm(g1, g0, 0x05040100u);
            B0[1] = __builtin_amdgcn_perm(g3, g2, 0x05040100u);
            B0[2] = __builtin_amdgcn_perm(g5, g4, 0x05040100u);
            B0[3] = __builtin_amdgcn_perm(g7, g6, 0x05040100u);
            B1[0] = __builtin_amdgcn_perm(g1, g0, 0x07060302u);
            B1[1] = __builtin_amdgcn_perm(g3, g2, 0x07060302u);
            B1[2] = __builtin_amdgcn_perm(g5, g4, 0x07060302u);
            B1[3] = __builtin_amdgcn_perm(g7, g6, 0x07060302u);
            acc0 = __builtin_amdgcn_mfma_f32_32x32x16_bf16(
                       __builtin_bit_cast(bf16x8, A),
                       __builtin_bit_cast(bf16x8, B0), acc0, 0, 0, 0);
            acc1 = __builtin_amdgcn_mfma_f32_32x32x16_bf16(
                       __builtin_bit_cast(bf16x8, A),
                       __builtin_bit_cast(bf16x8, B1), acc1, 0, 0, 0);
        }
        // C -> env LDS (fast pack; layout verified R9/R11)
        unsigned short* er = &env[i * ESTRIDE];
        #pragma unroll
        for (int q = 0; q < 3; q++) {
            int g = 2 * q + h;
            if (g < 5) {
                uint2 v0, v1;
                v0.x = pkbf2(acc0[4 * q + 0], acc0[4 * q + 1]);
                v0.y = pkbf2(acc0[4 * q + 2], acc0[4 * q + 3]);
                v1.x = pkbf2(acc1[4 * q + 0], acc1[4 * q + 1]);
                v1.y = pkbf2(acc1[4 * q + 2], acc1[4 * q + 3]);
                *(uint2*)&er[g * 128 + cl * 4]       = v0;
                *(uint2*)&er[640 + g * 128 + cl * 4] = v1;
            }
        }
        // self features (k'=1280..1343)
        unsigned sw = xb16[(size_t)a * 32 + (l >> 1)];
        er[K_ENV + l] = (unsigned short)(sw >> ((l & 1) * 16));
    }

    // phase-2 prefetch (ALL waves), issued BEFORE the barrier
    const int wq     = w & 3;
    const int ksbase = (w >> 2) * KSH;
    const unsigned short* wb = &WtB[((ksbase * 4 + wq) * 64 + l) * 8];
    s16x8 b0 = *(const s16x8*)(wb);
    s16x8 b1 = *(const s16x8*)(wb + 2048);
    s16x8 b2 = *(const s16x8*)(wb + 4096);
    s16x8 b3 = *(const s16x8*)(wb + 6144);
    float bs = (w < 4) ? bself[wq * 16 + (l & 15)] : 0.f;
    __syncthreads();                                      // env ready

    // ---- Phase 2: MFMA GEMM, 8 waves, 21 ks each, 4-deep pipeline ----
    {
        const int m16  = l & 15;
        const int quad = l >> 4;
        f32x4 acc = {0.f, 0.f, 0.f, 0.f};
        for (int kk = 0; kk < KSH; kk++) {
            int ks = ksbase + kk;
            s16x8 afrag = *(const s16x8*)&env[m16 * ESTRIDE + ks * 32 + quad * 8];
            s16x8 bcur = b0;
            b0 = b1; b1 = b2; b2 = b3;
            int nx = (kk + 4 < KSH) ? kk + 4 : KSH - 1;
            b3 = *(const s16x8*)(wb + (size_t)nx * 2048);
            acc = __builtin_amdgcn_mfma_f32_16x16x32_bf16(
                      __builtin_bit_cast(bf16x8, afrag),
                      __builtin_bit_cast(bf16x8, bcur), acc, 0, 0, 0);
        }
        // cross-wave K reduction through LDS (reuse pkl)
        float* red = (float*)pkl;
        if (w >= 4) {
            *(f32x4*)&red[((w - 4) * 64 + l) * 4] = acc;
        }
        __syncthreads();
        if (w < 4) {
            f32x4 other = *(const f32x4*)&red[(w * 64 + l) * 4];
            #pragma unroll
            for (int r = 0; r < 4; r++) {
                int row = quad * 4 + r;
                out[(size_t)(a0 + row) * NF + wq * 16 + m16] = acc[r] + other[r] + bs;
            }
        }
    }
}

// ---------------------------------------------------------------------------
extern "C" void kernel_launch(void* const* d_in, const int* in_sizes, int n_in,
                              void* d_out, int out_size, void* d_ws, size_t ws_size,
                              hipStream_t stream) {
    const float* x      = (const float*)d_in[0];
    const int*   first  = (const int*)d_in[1];
    const int*   second = (const int*)d_in[2];
    const float* dist   = (const float*)d_in[3];
    const float* mu     = (const float*)d_in[4];
    const float* sigma  = (const float*)d_in[5];
    const float* iw     = (const float*)d_in[6];
    const float* wself  = (const float*)d_in[7];
    const float* bself  = (const float*)d_in[8];
    float* out = (float*)d_out;

    char* ws = (char*)d_ws;
    unsigned short* WtB  = (unsigned short*)(ws);          // 172032 B
    int*            cnts = (int*)(ws + 172032);            // 120000 B
    float2*         msr  = (float2*)(ws + 292032);         // 160 B
    uint2*          pk   = (uint2*)(ws + 292192);          // 11520000 B
    unsigned*       xb16 = (unsigned*)(ws + 11812192);     // 3840000 B -> ~15.7 MB

    k_prep<<<dim3(161 + (N_ATOMS * 8 + 255) / 256), dim3(256), 0, stream>>>(
        iw, wself, mu, sigma, x, WtB, cnts, msr, xb16);
    k_scatter<<<dim3((N_PAIRS / 2 + 255) / 256), dim3(256), 0, stream>>>(
        first, second, dist, cnts, pk);
    k_main<<<dim3(N_ATOMS / BA), dim3(512), 0, stream>>>(
        xb16, cnts, pk, msr, WtB, bself, out);
}

// Round 12
// 116.439 us; speedup vs baseline: 2.9238x; 1.0062x over previous
//
#include <hip/hip_runtime.h>
#include <math.h>

#define N_ATOMS    30000
#define N_PAIRS    300000
#define CAP        48              // bucket capacity per atom; multiple of 16
#define NF         64
#define ND         20
#define K_ENV      1280            // 20nu * 64f (packed, no padding)
#define K_TOT      1344            // K_ENV + 64 self features
#define NKSTEP     42              // K_TOT / 32
#define KSH        21              // NKSTEP / 2 (per-wave K half in phase 2)
#define HARD_CUT   6.5f
#define BA         16              // atoms per block in main kernel
#define ESTRIDE    1352            // env row stride in u16 (1344+8 pad -> bank spread)
#define NM1        ((unsigned)(N_ATOMS - 1))

// inverse-distance quantization: invd in [1/6.5, 1/0.85] -> u16
#define INVD_LO    0.15384615385f
#define INVD_RANGE 1.02262443439f
#define QS         (65535.0f / INVD_RANGE)
#define DQ         (INVD_RANGE / 65535.0f)
// sqrt(0.5*log2(e)) -- folded so ar = lc - zz^2 (one fma less per senseval)
#define SQC        0.8493218002880191f

typedef short    s16x8  __attribute__((ext_vector_type(8)));
typedef __bf16   bf16x8 __attribute__((ext_vector_type(8)));
typedef unsigned u32x4  __attribute__((ext_vector_type(4)));
typedef float    f32x4  __attribute__((ext_vector_type(4)));
typedef float    f32x16 __attribute__((ext_vector_type(16)));

typedef __attribute__((address_space(1))) const void gconst_void;
typedef __attribute__((address_space(3))) void       lds_void;

__device__ __forceinline__ unsigned short f2bf(float x) {
    union { float f; unsigned u; } v; v.f = x;
    unsigned r = v.u + 0x7fffu + ((v.u >> 16) & 1u);   // RNE
    return (unsigned short)(r >> 16);
}
// RNE pack (one-time prep only)
__device__ __forceinline__ unsigned pkbf(float a, float b) {
    return (unsigned)f2bf(a) | ((unsigned)f2bf(b) << 16);
}
// fast pack: round-half-up + v_perm -> 3 VALU (hot loop; <=1 ULP vs RNE)
__device__ __forceinline__ unsigned pkbf2(float a, float b) {
    unsigned au = __float_as_uint(a) + 0x8000u;
    unsigned bu = __float_as_uint(b) + 0x8000u;
    return __builtin_amdgcn_perm(bu, au, 0x07060302u);  // {bu.hi16, au.hi16}
}
// R23 epilogue pack: single-instruction RNE pack (a in low 16).
__device__ __forceinline__ unsigned cvtpk(float a, float b) {
    unsigned r;
    asm("v_cvt_pk_bf16_f32 %0, %1, %2" : "=v"(r) : "v"(a), "v"(b));
    return r;
}
// R23 sense, 4 VALU-class ops: zz = u*zA' + zB' ; ar = lc - zz^2 ; exp2.
// Pad slots carry lc=-inf -> exact 0; nu>=20 lanes carry zB'=8.5e18 ->
// zz^2 ~ 7e37 finite -> ar <= -7e37 -> 0. No selects, no NaN paths.
__device__ __forceinline__ float senseval(unsigned w0, unsigned lcb,
                                          float zA, float zB) {
    float uu = (float)(w0 & 0xffffu);
    float zz = __builtin_fmaf(uu, zA, zB);
    float ar = __builtin_fmaf(zz, -zz, __uint_as_float(lcb));
    return __builtin_amdgcn_exp2f(ar);
}

// ---------------------------------------------------------------------------
// K0 (R23 FUSED prep+scatter; cnts zeroed by hipMemsetAsync before launch):
//  [0,42):  WtB bf16 B-frag pack (perm verified R9)
//  42:      msr
//  [43,981): x -> packed-bf16 table xb16
//  [981,1567): pair scatter into per-atom buckets (8B payload:
//             word0 = second<<16 | invd_u16, word1 = f32 log2(cut))
// prep and scatter touch disjoint buffers -> safe to run concurrently.
__global__ void k_ps(const float* __restrict__ iw, const float* __restrict__ wself,
                     const float* __restrict__ mu, const float* __restrict__ sigma,
                     const float* __restrict__ x,
                     const int* __restrict__ first, const int* __restrict__ second,
                     const float* __restrict__ dist,
                     unsigned short* __restrict__ WtB, int* __restrict__ cnts,
                     float2* __restrict__ msr, unsigned* __restrict__ xb16,
                     uint2* __restrict__ pk) {
    if (blockIdx.x < 42) {
        int idx = blockIdx.x * 256 + threadIdx.x;       // (ks*4+q)*64 + lane
        if (idx >= NKSTEP * 4 * 64) return;
        int l  = idx & 63;
        int q  = (idx >> 6) & 3;
        int ks = idx >> 8;
        int n  = q * 16 + (l & 15);
        int kb = ks * 32 + (l >> 4) * 8;
        u32x4 u;
        #pragma unroll
        for (int jj = 0; jj < 4; jj++) {
            unsigned short lo, hi;
            #pragma unroll
            for (int e = 0; e < 2; e++) {
                int k = kb + 2 * jj + e;
                float val;
                if (k < K_ENV) {
                    int t  = k / 640;
                    int rm = k - t * 640;
                    int g  = rm >> 7;
                    int c  = (rm & 127) >> 2;
                    int r  = k & 3;
                    int nu = 4 * g + r;
                    int f  = 2 * c + t;                  // even/odd tile split
                    val = iw[(nu * NF + n) * NF + f];
                } else {
                    val = wself[n * NF + (k - K_ENV)];
                }
                if (e == 0) lo = f2bf(val); else hi = f2bf(val);
            }
            u[jj] = (unsigned)lo | ((unsigned)hi << 16);
        }
        *(u32x4*)&WtB[idx * 8] = u;
    } else if (blockIdx.x == 42) {
        int i = threadIdx.x;
        if (i < ND) { float2 m; m.x = mu[i]; m.y = 1.0f / sigma[i]; msr[i] = m; }
    } else if (blockIdx.x < 981) {
        int o = (blockIdx.x - 43) * 256 + threadIdx.x;   // uint4 of xb16
        if (o < N_ATOMS * 32 / 4) {
            int wbase = o * 4;
            const float* src = &x[(size_t)wbase * 2];
            float2 f0 = *(const float2*)(src);
            float2 f1 = *(const float2*)(src + 2);
            float2 f2 = *(const float2*)(src + 4);
            float2 f3 = *(const float2*)(src + 6);
            u32x4 u;
            u[0] = pkbf(f0.x, f0.y);
            u[1] = pkbf(f1.x, f1.y);
            u[2] = pkbf(f2.x, f2.y);
            u[3] = pkbf(f3.x, f3.y);
            *(u32x4*)&xb16[wbase] = u;
        }
    } else {
        int p = ((blockIdx.x - 981) * 256 + threadIdx.x) * 2;
        if (p >= N_PAIRS) return;
        int2   f2 = *(const int2*)&first[p];
        int2   s2 = *(const int2*)&second[p];
        float2 d2 = *(const float2*)&dist[p];
        {
            float d    = d2.x;
            float invd = 1.0f / d;
            float tq   = fmaxf((invd - INVD_LO) * QS + 0.5f, 0.0f);
            unsigned u = min((unsigned)tq, 65535u);
            float co   = __cosf(0.2416609733530613f * d);    // 0.5*pi/6.5
            float lc   = fmaxf(__log2f(co * co), -10000.0f);
            int pos = atomicAdd(&cnts[f2.x], 1);
            if (pos < CAP) {
                uint2 v; v.x = ((unsigned)s2.x << 16) | u; v.y = __float_as_uint(lc);
                pk[(size_t)f2.x * CAP + pos] = v;
            }
        }
        {
            float d    = d2.y;
            float invd = 1.0f / d;
            float tq   = fmaxf((invd - INVD_LO) * QS + 0.5f, 0.0f);
            unsigned u = min((unsigned)tq, 65535u);
            float co   = __cosf(0.2416609733530613f * d);
            float lc   = fmaxf(__log2f(co * co), -10000.0f);
            int pos = atomicAdd(&cnts[f2.y], 1);
            if (pos < CAP) {
                uint2 v; v.x = ((unsigned)s2.y << 16) | u; v.y = __float_as_uint(lc);
                pk[(size_t)f2.y * CAP + pos] = v;
            }
        }
    }
}

// ---------------------------------------------------------------------------
// K2: 117.2us structure (R22) + R23 trims: (a) senseval down to 2 fma + exp2
// (NEXP2 folded via sqrt into zA/zB), (b) epilogue pack via single-inst
// v_cvt_pk_bf16_f32 (epilogue only -- m240: don't put asm cvt_pk in hot loop).
__global__ void __launch_bounds__(512, 6)
k_main(const unsigned* __restrict__ xb16, const int* __restrict__ cnts,
       const uint2* __restrict__ pk, const float2* __restrict__ msr,
       const unsigned short* __restrict__ WtB, const float* __restrict__ bself,
       float* __restrict__ out) {
    __shared__ unsigned short env[BA * ESTRIDE];          // 43264 B
    __shared__ uint2 pkl[BA * CAP];                       // 6144 B
    const int t  = threadIdx.x;
    const int w  = t >> 6;
    const int l  = t & 63;
    const int h  = l >> 5;
    const int cl = l & 31;
    const int a0 = blockIdx.x * BA;

    if (w < 6) {
        const char* gsrc = (const char*)(pk + (size_t)a0 * CAP) + (w * 64 + l) * 16;
        char* ldst = (char*)pkl + w * 1024;
        __builtin_amdgcn_global_load_lds((gconst_void*)gsrc, (lds_void*)ldst, 16, 0, 0);
    }

    float2 ms   = msr[min(cl, ND - 1)];
    const bool  nuok = (cl < ND);
    const float isig = ms.y;
    const float zA   = nuok ? DQ * isig * SQC : 0.0f;
    const float zB   = nuok ? ((INVD_LO - ms.x) * isig * SQC) : 8.493e18f;
    const unsigned* xw = xb16 + cl;

    const int cntA = min(cnts[a0 + 2 * w + 0], CAP);
    const int cntB = min(cnts[a0 + 2 * w + 1], CAP);

    __syncthreads();                                      // pkl staged

    // pad-poison slots [cnt,CAP): second=0 (safe gather), lc=-inf (sense->0).
    {
        uint2 pz; pz.x = 0u; pz.y = 0xFF800000u;
        if (l < CAP) {
            if (l >= cntA) pkl[(2 * w + 0) * CAP + l] = pz;
            if (l >= cntB) pkl[(2 * w + 1) * CAP + l] = pz;
        }
    }

    // ---- Phase 1: MFMA envsum (2 atoms per wave, sequential) ----
    #pragma unroll 1
    for (int ci = 0; ci < 2; ci++) {
        const int i = 2 * w + ci;
        const int a = a0 + i;
        const int cnt = ci ? cntB : cntA;
        const int nst = max((cnt + 15) >> 4, 1);
        const uint2* gb = &pkl[i * CAP];
        f32x16 acc0 = {0.f}, acc1 = {0.f};
        #pragma unroll 1
        for (int ks = 0; ks < nst; ks++) {
            const int k0 = ks * 16 + h * 8;
            const uint2* bp = gb + k0;
            uint4 q0 = *(const uint4*)(bp + 0);
            uint4 q1 = *(const uint4*)(bp + 2);
            uint4 q2 = *(const uint4*)(bp + 4);
            uint4 q3 = *(const uint4*)(bp + 6);
            unsigned g0 = xw[(q0.x >> 16) * 32];
            unsigned g1 = xw[(q0.z >> 16) * 32];
            unsigned g2 = xw[(q1.x >> 16) * 32];
            unsigned g3 = xw[(q1.z >> 16) * 32];
            unsigned g4 = xw[(q2.x >> 16) * 32];
            unsigned g5 = xw[(q2.z >> 16) * 32];
            unsigned g6 = xw[(q3.x >> 16) * 32];
            unsigned g7 = xw[(q3.z >> 16) * 32];
            u32x4 A, B0, B1;
            A[0] = pkbf2(senseval(q0.x, q0.y, zA, zB),
                         senseval(q0.z, q0.w, zA, zB));
            A[1] = pkbf2(senseval(q1.x, q1.y, zA, zB),
                         senseval(q1.z, q1.w, zA, zB));
            A[2] = pkbf2(senseval(q2.x, q2.y, zA, zB),
                         senseval(q2.z, q2.w, zA, zB));
            A[3] = pkbf2(senseval(q3.x, q3.y, zA, zB),
                         senseval(q3.z, q3.w, zA, zB));
            B0[0] = __builtin_amdgcn_perm(g1, g0, 0x05040100u);
            B0[1] = __builtin_amdgcn_perm(g3, g2, 0x05040100u);
            B0[2] = __builtin_amdgcn_perm(g5, g4, 0x05040100u);
            B0[3] = __builtin_amdgcn_perm(g7, g6, 0x05040100u);
            B1[0] = __builtin_amdgcn_perm(g1, g0, 0x07060302u);
            B1[1] = __builtin_amdgcn_perm(g3, g2, 0x07060302u);
            B1[2] = __builtin_amdgcn_perm(g5, g4, 0x07060302u);
            B1[3] = __builtin_amdgcn_perm(g7, g6, 0x07060302u);
            acc0 = __builtin_amdgcn_mfma_f32_32x32x16_bf16(
                       __builtin_bit_cast(bf16x8, A),
                       __builtin_bit_cast(bf16x8, B0), acc0, 0, 0, 0);
            acc1 = __builtin_amdgcn_mfma_f32_32x32x16_bf16(
                       __builtin_bit_cast(bf16x8, A),
                       __builtin_bit_cast(bf16x8, B1), acc1, 0, 0, 0);
        }
        // C -> env LDS (single-inst RNE packs; layout verified R9/R11)
        unsigned short* er = &env[i * ESTRIDE];
        #pragma unroll
        for (int q = 0; q < 3; q++) {
            int g = 2 * q + h;
            if (g < 5) {
                uint2 v0, v1;
                v0.x = cvtpk(acc0[4 * q + 0], acc0[4 * q + 1]);
                v0.y = cvtpk(acc0[4 * q + 2], acc0[4 * q + 3]);
                v1.x = cvtpk(acc1[4 * q + 0], acc1[4 * q + 1]);
                v1.y = cvtpk(acc1[4 * q + 2], acc1[4 * q + 3]);
                *(uint2*)&er[g * 128 + cl * 4]       = v0;
                *(uint2*)&er[640 + g * 128 + cl * 4] = v1;
            }
        }
        // self features (k'=1280..1343)
        unsigned sw = xb16[(size_t)a * 32 + (l >> 1)];
        er[K_ENV + l] = (unsigned short)(sw >> ((l & 1) * 16));
    }

    // phase-2 prefetch (ALL waves), issued BEFORE the barrier
    const int wq     = w & 3;
    const int ksbase = (w >> 2) * KSH;
    const unsigned short* wb = &WtB[((ksbase * 4 + wq) * 64 + l) * 8];
    s16x8 b0 = *(const s16x8*)(wb);
    s16x8 b1 = *(const s16x8*)(wb + 2048);
    s16x8 b2 = *(const s16x8*)(wb + 4096);
    s16x8 b3 = *(const s16x8*)(wb + 6144);
    float bs = (w < 4) ? bself[wq * 16 + (l & 15)] : 0.f;
    __syncthreads();                                      // env ready

    // ---- Phase 2: MFMA GEMM, 8 waves, 21 ks each, 4-deep pipeline ----
    {
        const int m16  = l & 15;
        const int quad = l >> 4;
        f32x4 acc = {0.f, 0.f, 0.f, 0.f};
        for (int kk = 0; kk < KSH; kk++) {
            int ks = ksbase + kk;
            s16x8 afrag = *(const s16x8*)&env[m16 * ESTRIDE + ks * 32 + quad * 8];
            s16x8 bcur = b0;
            b0 = b1; b1 = b2; b2 = b3;
            int nx = (kk + 4 < KSH) ? kk + 4 : KSH - 1;
            b3 = *(const s16x8*)(wb + (size_t)nx * 2048);
            acc = __builtin_amdgcn_mfma_f32_16x16x32_bf16(
                      __builtin_bit_cast(bf16x8, afrag),
                      __builtin_bit_cast(bf16x8, bcur), acc, 0, 0, 0);
        }
        // cross-wave K reduction through LDS (reuse pkl)
        float* red = (float*)pkl;
        if (w >= 4) {
            *(f32x4*)&red[((w - 4) * 64 + l) * 4] = acc;
        }
        __syncthreads();
        if (w < 4) {
            f32x4 other = *(const f32x4*)&red[(w * 64 + l) * 4];
            #pragma unroll
            for (int r = 0; r < 4; r++) {
                int row = quad * 4 + r;
                out[(size_t)(a0 + row) * NF + wq * 16 + m16] = acc[r] + other[r] + bs;
            }
        }
    }
}

// ---------------------------------------------------------------------------
extern "C" void kernel_launch(void* const* d_in, const int* in_sizes, int n_in,
                              void* d_out, int out_size, void* d_ws, size_t ws_size,
                              hipStream_t stream) {
    const float* x      = (const float*)d_in[0];
    const int*   first  = (const int*)d_in[1];
    const int*   second = (const int*)d_in[2];
    const float* dist   = (const float*)d_in[3];
    const float* mu     = (const float*)d_in[4];
    const float* sigma  = (const float*)d_in[5];
    const float* iw     = (const float*)d_in[6];
    const float* wself  = (const float*)d_in[7];
    const float* bself  = (const float*)d_in[8];
    float* out = (float*)d_out;

    char* ws = (char*)d_ws;
    unsigned short* WtB  = (unsigned short*)(ws);          // 172032 B
    int*            cnts = (int*)(ws + 172032);            // 120000 B
    float2*         msr  = (float2*)(ws + 292032);         // 160 B
    uint2*          pk   = (uint2*)(ws + 292192);          // 11520000 B
    unsigned*       xb16 = (unsigned*)(ws + 11812192);     // 3840000 B -> ~15.7 MB

    // zero cnts via memset node (graph-capturable), freeing the prep blocks
    hipMemsetAsync(cnts, 0, N_ATOMS * sizeof(int), stream);
    // fused prep + scatter (disjoint buffers; scatter ordered after memset)
    k_ps<<<dim3(981 + (N_PAIRS / 2 + 255) / 256), dim3(256), 0, stream>>>(
        iw, wself, mu, sigma, x, first, second, dist, WtB, cnts, msr, xb16, pk);
    k_main<<<dim3(N_ATOMS / BA), dim3(512), 0, stream>>>(
        xb16, cnts, pk, msr, WtB, bself, out);
}